// Round 6
// baseline (211.009 us; speedup 1.0000x reference)
//
#include <hip/hip_runtime.h>

#define VGRID 256
#define N_TAPS 27
#define CIN 64
#define COUT 64
#define BPTS 128     // points per block (2 groups of 16 per wave)
#define HBITS 20
#define HSIZE (1u << HBITS)          // 1M slots x 8 B = 8 MiB hash
#define HEMPTY 0xFFFFFFFFFFFFFFFFull // memset 0xFF => empty

typedef short short8 __attribute__((ext_vector_type(8)));   // 8 bf16
typedef float float4v __attribute__((ext_vector_type(4)));  // MFMA C/D + NT loads

__device__ __forceinline__ short f2bf(float x) {
    unsigned u = __builtin_bit_cast(unsigned, x);
    unsigned r = (u + 0x7FFF + ((u >> 16) & 1)) >> 16;  // RNE
    return (short)r;
}

__device__ __forceinline__ unsigned hslot(int lin) {
    return ((unsigned)lin * 2654435761u) >> (32 - HBITS);
}

// lookup for a voxel KNOWN to exist (bitmap-gated)
__device__ __forceinline__ int hlookup(const unsigned long long* __restrict__ hash,
                                       int lin) {
    unsigned s = hslot(lin);
    for (;;) {
        unsigned long long e = hash[s];
        if ((unsigned)(e >> 32) == (unsigned)lin) return (int)(unsigned)e;
        s = (s + 1) & (HSIZE - 1);
    }
}

// blocks [0,bt): hash insert + bitmap
// blocks [bt, bt+27): weight conversion to fragment-major bf16
// blocks [bt+27, ...): feats f32 -> bf16 streaming convert (nontemporal src)
__global__ void __launch_bounds__(256) build_kernel(
        const int* __restrict__ coords, unsigned long long* __restrict__ hash,
        unsigned* __restrict__ bits, const float* __restrict__ W,
        short* __restrict__ Wt, const float* __restrict__ F,
        short* __restrict__ Fb, int n, int bt_blocks, int fb_elems) {
    int b = (int)blockIdx.x;
    if (b >= bt_blocks + N_TAPS) {
        int idx = (b - bt_blocks - N_TAPS) * 256 + (int)threadIdx.x;
        int e = idx * 8;
        if (e < fb_elems) {
            const float4v* s = (const float4v*)(F + e);
            float4v x = __builtin_nontemporal_load(s);
            float4v y = __builtin_nontemporal_load(s + 1);
            short8 o = {f2bf(x[0]), f2bf(x[1]), f2bf(x[2]), f2bf(x[3]),
                        f2bf(y[0]), f2bf(y[1]), f2bf(y[2]), f2bf(y[3])};
            *(short8*)(Fb + e) = o;
        }
        return;
    }
    if (b >= bt_blocks) {
        int tap = b - bt_blocks;
        for (int e = threadIdx.x; e < CIN * COUT; e += 256) {
            int ci = e >> 6, co = e & 63;
            int ks = ci >> 5, quad = (ci >> 3) & 3, el = ci & 7;
            Wt[((((size_t)tap * 2 + ks) * 4 + quad) * 64 + co) * 8 + el] =
                f2bf(W[((size_t)tap * CIN + ci) * COUT + co]);
        }
        return;
    }
    int i = b * 256 + threadIdx.x;
    if (i >= n) return;
    int lin = (coords[i * 3 + 0] * VGRID + coords[i * 3 + 1]) * VGRID + coords[i * 3 + 2];
    // insert (lin -> i); duplicates keep max i (== ref last-write-wins since
    // high words equal, u64 atomicMax compares low words)
    unsigned long long want = ((unsigned long long)(unsigned)lin << 32) | (unsigned)i;
    unsigned s = hslot(lin);
    for (;;) {
        unsigned long long old = atomicCAS(&hash[s], HEMPTY, want);
        if (old == HEMPTY) break;
        if ((unsigned)(old >> 32) == (unsigned)lin) { atomicMax(&hash[s], want); break; }
        s = (s + 1) & (HSIZE - 1);
    }
    atomicOr(&bits[lin >> 5], 1u << (lin & 31));
}

// Gather-formulation conv: block=256 threads handles 128 points; each wave
// computes 2 MFMA groups (32 points). Probe split across thread pairs
// (t, t+128); results handed off via LDS. Grid 2048 blocks.
// Tap loop: MLP-2 batching (2 taps' fragment gathers in flight before MFMA),
// center tap folded into the same stream. All index lookups via 8 MiB hash.
__global__ void __launch_bounds__(256) fused_kernel(
        const int* __restrict__ coords, const unsigned long long* __restrict__ hash,
        const unsigned* __restrict__ bits, const short* __restrict__ featsb,
        const short* __restrict__ Wt, float* __restrict__ out, int n) {
    __shared__ int s_pk[BPTS];
    __shared__ unsigned s_hm[2][BPTS];
    __shared__ int s_jc[BPTS];
    __shared__ int s_p[4][BPTS];

    int t = threadIdx.x;
    int p = t & (BPTS - 1);
    int h = t >> 7;                      // half: 0 or 1
    int i = blockIdx.x * BPTS + p;

    // ---- phase 1: split probe (h=0 rows 0-4, h=1 rows 5-8) ----
    int cx = 0, cy = 0, cz = 0;
    unsigned pmask = 0;
    if (i < n) {
        cx = coords[i * 3 + 0];
        cy = coords[i * 3 + 1];
        cz = coords[i * 3 + 2];
        if (h == 0) s_jc[p] = hlookup(hash, (cx * VGRID + cy) * VGRID + cz);

        int zlo = cz > 0 ? cz - 1 : 0;
        int zhi = cz < VGRID - 1 ? cz + 1 : VGRID - 1;
        int wlo = zlo >> 5, whi = zhi >> 5;
        unsigned rwa[5], rwb[5];
#pragma unroll
        for (int rr = 0; rr < 5; ++rr) {
            int r = h * 5 + rr;
            int nx = cx + r / 3 - 1, ny = cy + r % 3 - 1;
            bool v = (r < 9) && ((unsigned)nx < VGRID) && ((unsigned)ny < VGRID);
            int rb = ((nx * VGRID + ny) * VGRID) >> 5;  // row base word (base %32==0)
            rwa[rr] = v ? bits[rb + wlo] : 0u;
            rwb[rr] = v ? bits[rb + whi] : 0u;
        }
#pragma unroll
        for (int rr = 0; rr < 5; ++rr) {
            int r = h * 5 + rr;
#pragma unroll
            for (int zz = 0; zz < 3; ++zz) {
                int k = r * 3 + zz;
                int nz = cz + zz - 1;
                if (r < 9 && k != 13 && (unsigned)nz < VGRID) {
                    unsigned wrd = ((nz >> 5) == wlo) ? rwa[rr] : rwb[rr];
                    pmask |= ((wrd >> (nz & 31)) & 1u) << k;
                }
            }
        }
    }
    if (h == 0) {
        s_pk[p] = (cx << 16) | (cy << 8) | cz;
        if (i >= n) s_jc[p] = 0;
    }
    s_hm[h][p] = pmask;
    __syncthreads();

    // ---- phase 2: combine masks; split j-prefetch (h: ranks 2h, 2h+1) ----
    {
        unsigned hmc = s_hm[0][p] | s_hm[1][p];
        if (h == 0) s_hm[0][p] = hmc;          // idempotent combine
        unsigned mm = hmc;
        if (h) { mm &= mm - 1u; if (mm) mm &= mm - 1u; }  // skip ranks 0,1
        int kA = -1, kB = -1;
        if (mm) { kA = __builtin_ctz(mm); mm &= mm - 1u;
                  if (mm) kB = __builtin_ctz(mm); }
        int ja = 0, jb = 0;
        if (kA >= 0)
            ja = hlookup(hash, ((cx + kA / 9 - 1) * VGRID + (cy + (kA / 3) % 3 - 1)) * VGRID
                               + (cz + kA % 3 - 1));
        if (kB >= 0)
            jb = hlookup(hash, ((cx + kB / 9 - 1) * VGRID + (cy + (kB / 3) % 3 - 1)) * VGRID
                               + (cz + kB % 3 - 1));
        s_p[2 * h + 0][p] = ja;
        s_p[2 * h + 1][p] = jb;
    }
    __syncthreads();

    // ---- phase 3: GEMM, 2 groups of 16 points per wave ----
    int wave = t >> 6, lane = t & 63;
    int m = lane & 15, quad = lane >> 4;
    const short8* Bp = (const short8*)Wt;
    const short8* Fp = (const short8*)featsb;   // 16B units; row j = 8 units
    int base = blockIdx.x * BPTS;

    for (int gg = 0; gg < 2; ++gg) {
        int g = wave * 2 + gg;
        int row = g * 16 + m;
        unsigned rhm = s_hm[0][row];
        int rjc = s_jc[row];

        unsigned gor = rhm;   // union over the 16 rows (quads hold same rows)
        gor |= (unsigned)__shfl_xor((int)gor, 1);
        gor |= (unsigned)__shfl_xor((int)gor, 2);
        gor |= (unsigned)__shfl_xor((int)gor, 4);
        gor |= (unsigned)__shfl_xor((int)gor, 8);
        gor = __builtin_amdgcn_readfirstlane(gor);

        float4v acc[4] = {{0,0,0,0},{0,0,0,0},{0,0,0,0},{0,0,0,0}};

        // fragment gather for tap k (zero rows where no hit; k=13 = center)
        auto loadfrag = [&](int k, short8& f0, short8& f1) {
            int j2 = -1;
            if (k == 13) {
                j2 = rjc;
            } else if ((rhm >> k) & 1u) {
                int rank = __builtin_popcount(rhm & ((1u << k) - 1u));
                if (rank < 4) {
                    j2 = s_p[rank][row];          // dynamic LDS index, not regs
                } else {
                    int rpk = s_pk[row];
                    int rx = (rpk >> 16) & 255, ry = (rpk >> 8) & 255, rz = rpk & 255;
                    j2 = hlookup(hash, ((rx + k / 9 - 1) * VGRID + (ry + (k / 3) % 3 - 1))
                                       * VGRID + (rz + k % 3 - 1));
                }
            }
            f0 = (short8){0,0,0,0,0,0,0,0};
            f1 = (short8){0,0,0,0,0,0,0,0};
            if (j2 >= 0) {
                f0 = Fp[(size_t)j2 * 8 + quad];
                f1 = Fp[(size_t)j2 * 8 + 4 + quad];
            }
        };

        // MLP-2 tap loop; center (13) folded into the stream
        unsigned gm = gor | (1u << 13);
        while (gm) {
            int k0 = (int)__builtin_ctz(gm); gm &= gm - 1u;
            int k1 = -1;
            if (gm) { k1 = (int)__builtin_ctz(gm); gm &= gm - 1u; }

            short8 x0, x1, y0, y1;
            loadfrag(k0, x0, x1);
            if (k1 >= 0) loadfrag(k1, y0, y1);

#pragma unroll
            for (int nt = 0; nt < 4; ++nt) {
                short8 b0 = Bp[((k0 * 2 + 0) * 4 + quad) * 64 + nt * 16 + m];
                short8 b1 = Bp[((k0 * 2 + 1) * 4 + quad) * 64 + nt * 16 + m];
                acc[nt] = __builtin_amdgcn_mfma_f32_16x16x32_bf16(x0, b0, acc[nt], 0, 0, 0);
                acc[nt] = __builtin_amdgcn_mfma_f32_16x16x32_bf16(x1, b1, acc[nt], 0, 0, 0);
            }
            if (k1 >= 0) {
#pragma unroll
                for (int nt = 0; nt < 4; ++nt) {
                    short8 b0 = Bp[((k1 * 2 + 0) * 4 + quad) * 64 + nt * 16 + m];
                    short8 b1 = Bp[((k1 * 2 + 1) * 4 + quad) * 64 + nt * 16 + m];
                    acc[nt] = __builtin_amdgcn_mfma_f32_16x16x32_bf16(y0, b0, acc[nt], 0, 0, 0);
                    acc[nt] = __builtin_amdgcn_mfma_f32_16x16x32_bf16(y1, b1, acc[nt], 0, 0, 0);
                }
            }
        }

        // store 16x64 tile, written exactly once; nontemporal (never re-read,
        // keeps L3 for the bf16 gather set)
#pragma unroll
        for (int nt = 0; nt < 4; ++nt)
#pragma unroll
            for (int r2 = 0; r2 < 4; ++r2) {
                int orow = base + g * 16 + quad * 4 + r2;
                if (orow < n)
                    __builtin_nontemporal_store(
                        acc[nt][r2], &out[(size_t)orow * COUT + nt * 16 + m]);
            }
    }
}

extern "C" void kernel_launch(void* const* d_in, const int* in_sizes, int n_in,
                              void* d_out, int out_size, void* d_ws, size_t ws_size,
                              hipStream_t stream) {
    const int* coords = (const int*)d_in[0];
    const float* feats = (const float*)d_in[1];
    const float* weights = (const float*)d_in[2];
    float* out = (float*)d_out;

    int n = in_sizes[0] / 3;  // 262144

    // layout: bits @0 (2 MiB) | hash @2 MiB (8 MiB) | Wt @10 MiB (216 KiB)
    //         | feats_bf @11 MiB (32 MiB)  => 43 MiB total
    char* ws = (char*)d_ws;
    size_t BITMAP_BYTES = (size_t)VGRID * VGRID * VGRID / 8;   // 2 MiB
    unsigned* bits = (unsigned*)ws;
    unsigned long long* hash = (unsigned long long*)(ws + BITMAP_BYTES);
    short* wbft = (short*)(ws + ((size_t)10 << 20));
    short* fb = (short*)(ws + ((size_t)11 << 20));

    // bitmap cleared to 0; hash cleared to 0xFF (= HEMPTY sentinel, also
    // immune to harness poison values)
    hipMemsetAsync(ws, 0, BITMAP_BYTES, stream);
    hipMemsetAsync(ws + BITMAP_BYTES, 0xFF, (size_t)HSIZE * 8, stream);

    int bt_blocks = (n + 255) / 256;
    int fb_elems = n * CIN;
    int conv_blocks = (fb_elems / 8 + 255) / 256;
    build_kernel<<<bt_blocks + N_TAPS + conv_blocks, 256, 0, stream>>>(
        coords, hash, bits, weights, wbft, feats, fb, n, bt_blocks, fb_elems);

    int f_blocks = (n + BPTS - 1) / BPTS;
    fused_kernel<<<f_blocks, 256, 0, stream>>>(coords, hash, bits, fb, wbft, out, n);
}

// Round 7
// 207.371 us; speedup vs baseline: 1.0175x; 1.0175x over previous
//
#include <hip/hip_runtime.h>

#define VGRID 256
#define N_TAPS 27
#define CIN 64
#define COUT 64
#define BPTS 64      // points per block (1 group of 16 per wave, 4 waves)
#define HBITS 20
#define HSIZE (1u << HBITS)          // 1M slots x 8 B = 8 MiB hash
#define HEMPTY 0xFFFFFFFFFFFFFFFFull // memset 0xFF => empty

typedef short short8 __attribute__((ext_vector_type(8)));   // 8 bf16
typedef float float4v __attribute__((ext_vector_type(4)));  // MFMA C/D + NT loads

__device__ __forceinline__ short f2bf(float x) {
    unsigned u = __builtin_bit_cast(unsigned, x);
    unsigned r = (u + 0x7FFF + ((u >> 16) & 1)) >> 16;  // RNE
    return (short)r;
}

__device__ __forceinline__ unsigned hslot(int lin) {
    return ((unsigned)lin * 2654435761u) >> (32 - HBITS);
}

// lookup for a voxel KNOWN to exist (bitmap-gated)
__device__ __forceinline__ int hlookup(const unsigned long long* __restrict__ hash,
                                       int lin) {
    unsigned s = hslot(lin);
    for (;;) {
        unsigned long long e = hash[s];
        if ((unsigned)(e >> 32) == (unsigned)lin) return (int)(unsigned)e;
        s = (s + 1) & (HSIZE - 1);
    }
}

// blocks [0,bt): hash insert + bitmap
// blocks [bt, bt+27): weight conversion to fragment-major bf16
// blocks [bt+27, ...): feats f32 -> bf16 streaming convert (nontemporal src)
__global__ void __launch_bounds__(256) build_kernel(
        const int* __restrict__ coords, unsigned long long* __restrict__ hash,
        unsigned* __restrict__ bits, const float* __restrict__ W,
        short* __restrict__ Wt, const float* __restrict__ F,
        short* __restrict__ Fb, int n, int bt_blocks, int fb_elems) {
    int b = (int)blockIdx.x;
    if (b >= bt_blocks + N_TAPS) {
        int idx = (b - bt_blocks - N_TAPS) * 256 + (int)threadIdx.x;
        int e = idx * 8;
        if (e < fb_elems) {
            const float4v* s = (const float4v*)(F + e);
            float4v x = __builtin_nontemporal_load(s);
            float4v y = __builtin_nontemporal_load(s + 1);
            short8 o = {f2bf(x[0]), f2bf(x[1]), f2bf(x[2]), f2bf(x[3]),
                        f2bf(y[0]), f2bf(y[1]), f2bf(y[2]), f2bf(y[3])};
            *(short8*)(Fb + e) = o;
        }
        return;
    }
    if (b >= bt_blocks) {
        int tap = b - bt_blocks;
        for (int e = threadIdx.x; e < CIN * COUT; e += 256) {
            int ci = e >> 6, co = e & 63;
            int ks = ci >> 5, quad = (ci >> 3) & 3, el = ci & 7;
            Wt[((((size_t)tap * 2 + ks) * 4 + quad) * 64 + co) * 8 + el] =
                f2bf(W[((size_t)tap * CIN + ci) * COUT + co]);
        }
        return;
    }
    int i = b * 256 + threadIdx.x;
    if (i >= n) return;
    int lin = (coords[i * 3 + 0] * VGRID + coords[i * 3 + 1]) * VGRID + coords[i * 3 + 2];
    // insert (lin -> i); duplicates keep max i (== ref last-write-wins since
    // high words equal, u64 atomicMax compares low words)
    unsigned long long want = ((unsigned long long)(unsigned)lin << 32) | (unsigned)i;
    unsigned s = hslot(lin);
    for (;;) {
        unsigned long long old = atomicCAS(&hash[s], HEMPTY, want);
        if (old == HEMPTY) break;
        if ((unsigned)(old >> 32) == (unsigned)lin) { atomicMax(&hash[s], want); break; }
        s = (s + 1) & (HSIZE - 1);
    }
    atomicOr(&bits[lin >> 5], 1u << (lin & 31));
}

// Gather-formulation conv: block=256 threads handles 64 points; each wave
// owns ONE 16-row MFMA group. Probe split 4-ways across quarter-threads
// (q = wave): q0 rows{0,1}+center-j, q1 rows{2,3}, q2 rows{4,5}, q3
// rows{6,7,8}; each quarter prefetches neighbor rank q. Grid 4096 blocks
// (2 residency rounds -> scheduler backfill evens out block imbalance).
// Simple single-tap loop (round-6 MLP-2 batching was VALU-negative).
// Regular out stores (NT stores caused +28 MB partial-line amplification).
__global__ void __launch_bounds__(256) fused_kernel(
        const int* __restrict__ coords, const unsigned long long* __restrict__ hash,
        const unsigned* __restrict__ bits, const short* __restrict__ featsb,
        const short* __restrict__ Wt, float* __restrict__ out, int n) {
    __shared__ int s_pk[BPTS];
    __shared__ unsigned s_hm[4][BPTS];
    __shared__ int s_jc[BPTS];
    __shared__ int s_p[4][BPTS];

    int t = threadIdx.x;
    int p = t & (BPTS - 1);
    int q = t >> 6;                      // quarter == wave index
    int i = blockIdx.x * BPTS + p;

    // ---- phase 1: 4-way split probe ----
    int cx = 0, cy = 0, cz = 0;
    unsigned pmask = 0;
    if (i < n) {
        cx = coords[i * 3 + 0];
        cy = coords[i * 3 + 1];
        cz = coords[i * 3 + 2];
        if (q == 0) s_jc[p] = hlookup(hash, (cx * VGRID + cy) * VGRID + cz);

        int zlo = cz > 0 ? cz - 1 : 0;
        int zhi = cz < VGRID - 1 ? cz + 1 : VGRID - 1;
        int wlo = zlo >> 5, whi = zhi >> 5;
        int nr = (q == 3) ? 3 : 2;       // rows handled by this quarter
        int r0 = 2 * q;
        unsigned rwa[3], rwb[3];
#pragma unroll
        for (int rr = 0; rr < 3; ++rr) {
            int r = r0 + rr;
            int nx = cx + r / 3 - 1, ny = cy + r % 3 - 1;
            bool v = (rr < nr) && ((unsigned)nx < VGRID) && ((unsigned)ny < VGRID);
            int rb = ((nx * VGRID + ny) * VGRID) >> 5;  // row base word (base %32==0)
            rwa[rr] = v ? bits[rb + wlo] : 0u;
            rwb[rr] = v ? bits[rb + whi] : 0u;
        }
#pragma unroll
        for (int rr = 0; rr < 3; ++rr) {
            int r = r0 + rr;
#pragma unroll
            for (int zz = 0; zz < 3; ++zz) {
                int k = r * 3 + zz;
                int nz = cz + zz - 1;
                if (rr < nr && k != 13 && (unsigned)nz < VGRID) {
                    unsigned wrd = ((nz >> 5) == wlo) ? rwa[rr] : rwb[rr];
                    pmask |= ((wrd >> (nz & 31)) & 1u) << k;
                }
            }
        }
    }
    if (q == 0) {
        s_pk[p] = (cx << 16) | (cy << 8) | cz;
        if (i >= n) s_jc[p] = 0;
    }
    s_hm[q][p] = pmask;
    __syncthreads();

    // ---- phase 2: combine masks; quarter q prefetches rank q ----
    {
        unsigned hmc = s_hm[0][p] | s_hm[1][p] | s_hm[2][p] | s_hm[3][p];
        if (q == 0) s_hm[0][p] = hmc;    // idempotent combine
        unsigned mm = hmc;
#pragma unroll
        for (int d = 0; d < 3; ++d) if (d < q) mm &= mm - 1u;  // drop q lowest
        int ja = 0;
        if (mm) {
            int kA = __builtin_ctz(mm);
            ja = hlookup(hash, ((cx + kA / 9 - 1) * VGRID + (cy + (kA / 3) % 3 - 1))
                               * VGRID + (cz + kA % 3 - 1));
        }
        s_p[q][p] = ja;
    }
    __syncthreads();

    // ---- phase 3: GEMM, one 16-row group per wave ----
    int lane = t & 63;
    int m = lane & 15, quad = lane >> 4;
    const short8* Bp = (const short8*)Wt;
    const short8* Fp = (const short8*)featsb;   // 16B units; row j = 8 units
    int base = blockIdx.x * BPTS;

    int row = q * 16 + m;
    unsigned rhm = s_hm[0][row];
    int rjc = s_jc[row];

    unsigned gor = rhm;   // union over the 16 rows (quads hold same rows)
    gor |= (unsigned)__shfl_xor((int)gor, 1);
    gor |= (unsigned)__shfl_xor((int)gor, 2);
    gor |= (unsigned)__shfl_xor((int)gor, 4);
    gor |= (unsigned)__shfl_xor((int)gor, 8);
    gor = __builtin_amdgcn_readfirstlane(gor);

    float4v acc[4] = {{0,0,0,0},{0,0,0,0},{0,0,0,0},{0,0,0,0}};

    // center tap (13): A gathered straight to registers
    {
        short8 a0 = Fp[(size_t)rjc * 8 + quad];
        short8 a1 = Fp[(size_t)rjc * 8 + 4 + quad];
#pragma unroll
        for (int nt = 0; nt < 4; ++nt) {
            short8 b0 = Bp[((13 * 2 + 0) * 4 + quad) * 64 + nt * 16 + m];
            short8 b1 = Bp[((13 * 2 + 1) * 4 + quad) * 64 + nt * 16 + m];
            acc[nt] = __builtin_amdgcn_mfma_f32_16x16x32_bf16(a0, b0, acc[nt], 0, 0, 0);
            acc[nt] = __builtin_amdgcn_mfma_f32_16x16x32_bf16(a1, b1, acc[nt], 0, 0, 0);
        }
    }

    // neighbor taps present anywhere in this 16-row group
    unsigned gm = gor;
    while (gm) {
        int k = (int)__builtin_ctz(gm); gm &= gm - 1u;
        bool has = (rhm >> k) & 1u;
        short8 h0 = {0,0,0,0,0,0,0,0}, h1 = {0,0,0,0,0,0,0,0};
        if (has) {
            int rank = __builtin_popcount(rhm & ((1u << k) - 1u));
            int j2;
            if (rank < 4) {
                j2 = s_p[rank][row];          // dynamic LDS index, not regs
            } else {
                int rpk = s_pk[row];
                int rx = (rpk >> 16) & 255, ry = (rpk >> 8) & 255, rz = rpk & 255;
                j2 = hlookup(hash, ((rx + k / 9 - 1) * VGRID + (ry + (k / 3) % 3 - 1))
                                   * VGRID + (rz + k % 3 - 1));
            }
            h0 = Fp[(size_t)j2 * 8 + quad];
            h1 = Fp[(size_t)j2 * 8 + 4 + quad];
        }
#pragma unroll
        for (int nt = 0; nt < 4; ++nt) {
            short8 b0 = Bp[((k * 2 + 0) * 4 + quad) * 64 + nt * 16 + m];
            short8 b1 = Bp[((k * 2 + 1) * 4 + quad) * 64 + nt * 16 + m];
            acc[nt] = __builtin_amdgcn_mfma_f32_16x16x32_bf16(h0, b0, acc[nt], 0, 0, 0);
            acc[nt] = __builtin_amdgcn_mfma_f32_16x16x32_bf16(h1, b1, acc[nt], 0, 0, 0);
        }
    }

    // store 16x64 tile, written exactly once; REGULAR stores (L2 assembles
    // full lines -> WRITE_SIZE == output size)
#pragma unroll
    for (int nt = 0; nt < 4; ++nt)
#pragma unroll
        for (int r2 = 0; r2 < 4; ++r2) {
            int orow = base + q * 16 + quad * 4 + r2;
            if (orow < n) out[(size_t)orow * COUT + nt * 16 + m] = acc[nt][r2];
        }
}

extern "C" void kernel_launch(void* const* d_in, const int* in_sizes, int n_in,
                              void* d_out, int out_size, void* d_ws, size_t ws_size,
                              hipStream_t stream) {
    const int* coords = (const int*)d_in[0];
    const float* feats = (const float*)d_in[1];
    const float* weights = (const float*)d_in[2];
    float* out = (float*)d_out;

    int n = in_sizes[0] / 3;  // 262144

    // layout: bits @0 (2 MiB) | hash @2 MiB (8 MiB) | Wt @10 MiB (216 KiB)
    //         | feats_bf @11 MiB (32 MiB)  => 43 MiB total
    char* ws = (char*)d_ws;
    size_t BITMAP_BYTES = (size_t)VGRID * VGRID * VGRID / 8;   // 2 MiB
    unsigned* bits = (unsigned*)ws;
    unsigned long long* hash = (unsigned long long*)(ws + BITMAP_BYTES);
    short* wbft = (short*)(ws + ((size_t)10 << 20));
    short* fb = (short*)(ws + ((size_t)11 << 20));

    // bitmap cleared to 0; hash cleared to 0xFF (= HEMPTY sentinel, also
    // immune to harness poison values)
    hipMemsetAsync(ws, 0, BITMAP_BYTES, stream);
    hipMemsetAsync(ws + BITMAP_BYTES, 0xFF, (size_t)HSIZE * 8, stream);

    int bt_blocks = (n + 255) / 256;
    int fb_elems = n * CIN;
    int conv_blocks = (fb_elems / 8 + 255) / 256;
    build_kernel<<<bt_blocks + N_TAPS + conv_blocks, 256, 0, stream>>>(
        coords, hash, bits, weights, wbft, feats, fb, n, bt_blocks, fb_elems);

    int f_blocks = (n + BPTS - 1) / BPTS;
    fused_kernel<<<f_blocks, 256, 0, stream>>>(coords, hash, bits, fb, wbft, out, n);
}